// Round 1
// baseline (135.825 us; speedup 1.0000x reference)
//
#include <hip/hip_runtime.h>

typedef _Float16 half8 __attribute__((ext_vector_type(8)));
typedef _Float16 half4_t __attribute__((ext_vector_type(4)));
typedef float float4_t __attribute__((ext_vector_type(4)));

#define NH 128
#define SB 64            // samples per block
#define NT 256           // threads per block

// d_ws fp16 element offsets
#define OFF_W1   0       // [128][32] chunk-major, k>=6 zero-padded
#define OFF_W21  4096
#define OFF_W22  20480
#define OFF_WM1  36864
#define OFF_WM2  53248
#define OFF_W4   69632   // [5][128] row-major (fc31 rows 0-2, fc32 rows 3-4)
#define WS_ELEMS 70272

__device__ __forceinline__ float fast_tanh(float x) {
  x = fminf(15.f, fmaxf(-15.f, x));
  float e = __builtin_amdgcn_exp2f(x * 2.8853900817779268f);   // e^(2x)
  return (e - 1.f) * __builtin_amdgcn_rcpf(e + 1.f);
}
__device__ __forceinline__ float sigmoid4(float z) {
  z = fminf(30.f, fmaxf(-30.f, z));
  float e = __builtin_amdgcn_exp2f(-z * 1.4426950408889634f);  // e^(-z)
  return 4.f * __builtin_amdgcn_rcpf(1.f + e);
}

// Convert fp32 weights -> fp16 in ws, permuted into MFMA-A-fragment chunk order:
// chunk layout: dst = ((mt*KC + k8)*16 + (row&15))*8 + (k&7), mt=row>>4, k8=k>>3
__global__ void prepack(const float* __restrict__ w1, const float* __restrict__ w21,
                        const float* __restrict__ w22, const float* __restrict__ wm1,
                        const float* __restrict__ wm2, const float* __restrict__ w31,
                        const float* __restrict__ w32, _Float16* __restrict__ ws) {
  for (int i = blockIdx.x * blockDim.x + threadIdx.x; i < WS_ELEMS;
       i += gridDim.x * blockDim.x) {
    float v;
    if (i < OFF_W21) {                       // W1: [128][32], KC=4
      int t = i;
      int j = t & 7, c = t >> 3, l16 = c & 15, t1 = c >> 4;
      int k8 = t1 & 3, mt = t1 >> 2;
      int row = mt * 16 + l16, k = k8 * 8 + j;
      v = (k < 6) ? w1[row * 6 + k] : 0.f;
    } else if (i < OFF_W4) {                 // four 128x128, KC=16
      int t = i - OFF_W21;
      int m = t >> 14; t &= 16383;
      const float* src = (m == 0) ? w21 : (m == 1) ? w22 : (m == 2) ? wm1 : wm2;
      int j = t & 7, c = t >> 3, l16 = c & 15, t1 = c >> 4;
      int k8 = t1 & 15, mt = t1 >> 4;
      v = src[(mt * 16 + l16) * 128 + k8 * 8 + j];
    } else {                                 // W4 row-major [5][128]
      int t = i - OFF_W4;
      int r = t >> 7, k = t & 127;
      v = (r < 3) ? w31[r * 128 + k] : w32[(r - 3) * 128 + k];
    }
    ws[i] = (_Float16)v;
  }
}

// One 128x64 GEMM layer: C[o][s] = tanh(W @ act^T + b), output written as the
// next layer's B operand in chunk-major LDS layout.
// Wave wv handles m-tiles {2wv, 2wv+1}, all 4 n-tiles (64 samples).
template <int K>
__device__ __forceinline__ void gemm_layer(const _Float16* __restrict__ Wg,
                                           const _Float16* __restrict__ inB,
                                           const float* __restrict__ biasL,
                                           _Float16* __restrict__ outB) {
  constexpr int KC = K / 8;   // 16B chunks per row
  constexpr int KS = K / 32;  // k-steps
  const int tid  = threadIdx.x;
  const int wv   = tid >> 6;
  const int lane = tid & 63;
  const int quad = lane >> 4;
  const int l16  = lane & 15;
  const int mt0 = wv * 2, mt1 = mt0 + 1;

  half8 a0[KS], a1[KS];
#pragma unroll
  for (int kk = 0; kk < KS; ++kk) {
    a0[kk] = *(const half8*)(Wg + ((mt0 * KC + kk * 4 + quad) * 16 + l16) * 8);
    a1[kk] = *(const half8*)(Wg + ((mt1 * KC + kk * 4 + quad) * 16 + l16) * 8);
  }
  float4_t acc0[4], acc1[4];
#pragma unroll
  for (int nt = 0; nt < 4; ++nt) {
    acc0[nt] = (float4_t){0.f, 0.f, 0.f, 0.f};
    acc1[nt] = (float4_t){0.f, 0.f, 0.f, 0.f};
  }
#pragma unroll
  for (int kk = 0; kk < KS; ++kk) {
#pragma unroll
    for (int nt = 0; nt < 4; ++nt) {
      half8 b = *(const half8*)(inB + (kk * 4 + quad) * 512 + (nt * 16 + l16) * 8);
      acc0[nt] = __builtin_amdgcn_mfma_f32_16x16x32_f16(a0[kk], b, acc0[nt], 0, 0, 0);
      acc1[nt] = __builtin_amdgcn_mfma_f32_16x16x32_f16(a1[kk], b, acc1[nt], 0, 0, 0);
    }
  }
  const float4_t bv0 = *(const float4_t*)(biasL + mt0 * 16 + quad * 4);
  const float4_t bv1 = *(const float4_t*)(biasL + mt1 * 16 + quad * 4);
  const int ob0 = mt0 * 16 + quad * 4;
  const int ob1 = mt1 * 16 + quad * 4;
#pragma unroll
  for (int nt = 0; nt < 4; ++nt) {
    const int s = nt * 16 + l16;
    half4_t h0, h1;
#pragma unroll
    for (int r = 0; r < 4; ++r) {
      h0[r] = (_Float16)fast_tanh(acc0[nt][r] + bv0[r]);
      h1[r] = (_Float16)fast_tanh(acc1[nt][r] + bv1[r]);
    }
    *(half4_t*)(outB + (ob0 >> 3) * 512 + s * 8 + (ob0 & 7)) = h0;
    *(half4_t*)(outB + (ob1 >> 3) * 512 + s * 8 + (ob1 & 7)) = h1;
  }
}

__global__ __launch_bounds__(NT) void bnet_main(
    const float* __restrict__ x, const float* __restrict__ meang,
    const float* __restrict__ stdg, const float* __restrict__ b1,
    const float* __restrict__ b21, const float* __restrict__ b22,
    const float* __restrict__ bm1, const float* __restrict__ bm2,
    const float* __restrict__ b31, const float* __restrict__ b32,
    const _Float16* __restrict__ ws, float* __restrict__ out) {
  __shared__ __align__(16) _Float16 bufH[SB * NH];
  __shared__ __align__(16) _Float16 bufA[SB * NH];
  __shared__ __align__(16) _Float16 bufB[SB * NH];
  __shared__ __align__(16) _Float16 xb[SB * 32];
  __shared__ __align__(16) float bias_lds[5 * 128];
  __shared__ __align__(16) float part[NT * 5];

  const int tid = threadIdx.x;
  const int s0 = blockIdx.x * SB;

  // stage biases (fc1,fc21,fc22,fcm1,fcm2)
  for (int i = tid; i < 640; i += NT) {
    int layer = i >> 7, idx = i & 127;
    const float* src = (layer == 0) ? b1 : (layer == 1) ? b21
                     : (layer == 2) ? b22 : (layer == 3) ? bm1 : bm2;
    bias_lds[i] = src[idx];
  }
  // stage x -> xb chunk-major (K=32, zero-padded past k=5)
  {
    half8 v;
#pragma unroll
    for (int j = 0; j < 8; ++j) v[j] = (_Float16)0.f;
    if ((tid >> 6) == 0) {
      const float* xp = x + (size_t)(s0 + (tid & 63)) * 6;
#pragma unroll
      for (int j = 0; j < 6; ++j) v[j] = (_Float16)xp[j];
    }
    *(half8*)(xb + tid * 8) = v;   // addr = k8*512 + s*8 == tid*8
  }
  __syncthreads();

  gemm_layer<32>(ws + OFF_W1, xb, bias_lds, bufH);          // h
  __syncthreads();
  gemm_layer<128>(ws + OFF_W21, bufH, bias_lds + 128, bufA); // x21
  gemm_layer<128>(ws + OFF_W22, bufH, bias_lds + 256, bufB); // x22
  __syncthreads();
  gemm_layer<128>(ws + OFF_WM1, bufA, bias_lds + 384, bufH); // xm1 -> bufH
  __syncthreads();
  gemm_layer<128>(ws + OFF_WM2, bufB, bias_lds + 512, bufA); // xm2 -> bufA
  __syncthreads();

  // L4 partial dot products: 5 outputs x 64 samples, k split over 4 quarters
  {
    const int s = tid & 63, q = tid >> 6;
#pragma unroll
    for (int j = 0; j < 5; ++j) {
      const _Float16* xm = (j < 3) ? bufH : bufA;
      const _Float16* wr = ws + OFF_W4 + j * 128 + q * 32;
      float acc = 0.f;
#pragma unroll
      for (int c = 0; c < 4; ++c) {
        half8 xv = *(const half8*)(xm + (q * 4 + c) * 512 + s * 8);
        half8 wv = *(const half8*)(wr + c * 8);
#pragma unroll
        for (int e = 0; e < 8; ++e) acc += (float)xv[e] * (float)wv[e];
      }
      part[tid * 5 + j] = acc;
    }
  }
  __syncthreads();

  if (tid < SB) {
    const int s = tid;
    float r[5];
#pragma unroll
    for (int j = 0; j < 5; ++j)
      r[j] = part[s * 5 + j] + part[(64 + s) * 5 + j] +
             part[(128 + s) * 5 + j] + part[(192 + s) * 5 + j];
    float u0 = -(r[0] + b31[0]);
    float u1 = -(r[1] + b31[1]);
    float u2 = -(r[2] + b31[2]);
    float p0 = sigmoid4(r[3] + b32[0]);
    float p1 = sigmoid4(r[4] + b32[1]);
    const float* xp = x + (size_t)(s0 + s) * 6;
    float px = xp[0] * stdg[0] + meang[0];
    float vx = xp[1] * stdg[1] + meang[1];
    float py = xp[2] * stdg[2] + meang[2];
    float vy = xp[3] * stdg[3] + meang[3];
    float pz = xp[4] * stdg[4] + meang[4];
    float vz = xp[5] * stdg[5] + meang[5];
    float dx = px - 10.f, dy = py - 10.f, dz = pz - 9.f;
    float dx2 = dx * dx, dy2 = dy * dy, dz2 = dz * dz;
    float dx3 = dx2 * dx, dy3 = dy2 * dy, dz3 = dz2 * dz;
    float barrier = dx3 * dx + dy3 * dy + dz3 * dz - 2401.f;  // R^4 = 7^4
    float bdot = 4.f * (dx3 * vx + dy3 * vy + dz3 * vz);
    float Lf2b = 12.f * (dx2 * vx * vx + dy2 * vy * vy + dz2 * vz * vz);
    float g0 = -4.f * dx3, g1 = -4.f * dy3, g2 = -4.f * dz3;
    float hv = Lf2b + (p0 + p1) * bdot + p0 * p1 * barrier;
    float Gu = g0 * u0 + g1 * u1 + g2 * u2;
    float GG = g0 * g0 + g1 * g1 + g2 * g2;
    float lam = fmaxf(Gu - hv, 0.f) / GG;
    float* op = out + (size_t)(s0 + s) * 3;
    op[0] = u0 - lam * g0;
    op[1] = u1 - lam * g1;
    op[2] = u2 - lam * g2;
  }
}

extern "C" void kernel_launch(void* const* d_in, const int* in_sizes, int n_in,
                              void* d_out, int out_size, void* d_ws, size_t ws_size,
                              hipStream_t stream) {
  const float* x    = (const float*)d_in[0];
  const float* mean = (const float*)d_in[1];
  const float* stdv = (const float*)d_in[2];
  const float* w1   = (const float*)d_in[3];
  const float* b1   = (const float*)d_in[4];
  const float* w21  = (const float*)d_in[5];
  const float* b21  = (const float*)d_in[6];
  const float* w22  = (const float*)d_in[7];
  const float* b22  = (const float*)d_in[8];
  const float* wm1  = (const float*)d_in[9];
  const float* bm1  = (const float*)d_in[10];
  const float* wm2  = (const float*)d_in[11];
  const float* bm2  = (const float*)d_in[12];
  const float* w31  = (const float*)d_in[13];
  const float* b31  = (const float*)d_in[14];
  const float* w32  = (const float*)d_in[15];
  const float* b32  = (const float*)d_in[16];
  _Float16* ws = (_Float16*)d_ws;
  float* out = (float*)d_out;
  const int batch = in_sizes[0] / 6;

  hipLaunchKernelGGL(prepack, dim3(96), dim3(NT), 0, stream,
                     w1, w21, w22, wm1, wm2, w31, w32, ws);
  hipLaunchKernelGGL(bnet_main, dim3(batch / SB), dim3(NT), 0, stream,
                     x, mean, stdv, b1, b21, b22, bm1, bm2, b31, b32,
                     (const _Float16*)ws, out);
}

// Round 2
// 134.804 us; speedup vs baseline: 1.0076x; 1.0076x over previous
//
#include <hip/hip_runtime.h>

typedef _Float16 half8 __attribute__((ext_vector_type(8)));
typedef _Float16 half4_t __attribute__((ext_vector_type(4)));
typedef float float4_t __attribute__((ext_vector_type(4)));

#define SB 32            // samples per block
#define NT 256           // threads per block

// d_ws fp16 element offsets (weights, MFMA-chunk-major) + fp32 bias block
#define OFF_W1   0       // [128][32] chunk-major, k>=6 zero-padded
#define OFF_W21  4096
#define OFF_W22  20480
#define OFF_WM1  36864
#define OFF_WM2  53248
#define OFF_W4   69632   // [5][128] row-major (fc31 rows 0-2, fc32 rows 3-4)
#define OFF_BIAS 70272   // fp32[640]: b1,b21,b22,bm1,bm2 (cast region)
#define WS_WELEMS 70272

__device__ __forceinline__ float fast_tanh(float x) {
  // tanh(x) = 1 - 2/(1+e^{2x}); exp2 path, no clamps (inf-safe)
  float e = __builtin_amdgcn_exp2f(x * 2.8853900817779268f);
  return fmaf(-2.f, __builtin_amdgcn_rcpf(1.f + e), 1.f);
}
__device__ __forceinline__ float sigmoid4(float z) {
  float e = __builtin_amdgcn_exp2f(-z * 1.4426950408889634f);
  return 4.f * __builtin_amdgcn_rcpf(1.f + e);
}

// fp32 weights -> fp16 chunk-major in ws + fp32 bias block.
// chunk layout: dst = ((mt*KC + k8)*16 + (row&15))*8 + (k&7)
__global__ void prepack(const float* __restrict__ w1, const float* __restrict__ w21,
                        const float* __restrict__ w22, const float* __restrict__ wm1,
                        const float* __restrict__ wm2, const float* __restrict__ w31,
                        const float* __restrict__ w32, const float* __restrict__ b1,
                        const float* __restrict__ b21, const float* __restrict__ b22,
                        const float* __restrict__ bm1, const float* __restrict__ bm2,
                        _Float16* __restrict__ ws) {
  const int stride = gridDim.x * blockDim.x;
  for (int i = blockIdx.x * blockDim.x + threadIdx.x; i < WS_WELEMS; i += stride) {
    float v;
    if (i < OFF_W21) {                       // W1: [128][32], KC=4
      int t = i;
      int j = t & 7, c = t >> 3, l16 = c & 15, t1 = c >> 4;
      int k8 = t1 & 3, mt = t1 >> 2;
      int row = mt * 16 + l16, k = k8 * 8 + j;
      v = (k < 6) ? w1[row * 6 + k] : 0.f;
    } else if (i < OFF_W4) {                 // four 128x128, KC=16
      int t = i - OFF_W21;
      int m = t >> 14; t &= 16383;
      const float* src = (m == 0) ? w21 : (m == 1) ? w22 : (m == 2) ? wm1 : wm2;
      int j = t & 7, c = t >> 3, l16 = c & 15, t1 = c >> 4;
      int k8 = t1 & 15, mt = t1 >> 4;
      v = src[(mt * 16 + l16) * 128 + k8 * 8 + j];
    } else {                                 // W4 row-major [5][128]
      int t = i - OFF_W4;
      int r = t >> 7, k = t & 127;
      v = (r < 3) ? w31[r * 128 + k] : w32[(r - 3) * 128 + k];
    }
    ws[i] = (_Float16)v;
  }
  float* bws = (float*)(ws + OFF_BIAS);
  for (int i = blockIdx.x * blockDim.x + threadIdx.x; i < 640; i += stride) {
    int layer = i >> 7, idx = i & 127;
    const float* src = (layer == 0) ? b1 : (layer == 1) ? b21
                     : (layer == 2) ? b22 : (layer == 3) ? bm1 : bm2;
    bws[i] = src[idx];
  }
}

// One 128xSB GEMM layer: out[o][s] = tanh(W @ act^T + b), output written in
// chunk-major LDS layout (next layer's B operand).
// Wave wv handles m-tiles {2wv, 2wv+1}, all SB/16 n-tiles.
template <int K, int SBX>
__device__ __forceinline__ void gemm_layer(const _Float16* __restrict__ Wg,
                                           const _Float16* __restrict__ inB,
                                           const float* __restrict__ biasG,
                                           _Float16* __restrict__ outB) {
  constexpr int KC = K / 8;    // 16B chunks per row
  constexpr int KS = K / 32;   // k-steps
  constexpr int NTT = SBX / 16;
  constexpr int RS = SBX * 8;  // chunk-row stride in elems
  const int tid  = threadIdx.x;
  const int wv   = tid >> 6;
  const int lane = tid & 63;
  const int quad = lane >> 4;
  const int l16  = lane & 15;
  const int mt0 = wv * 2, mt1 = mt0 + 1;

  half8 a0[KS], a1[KS];
#pragma unroll
  for (int kk = 0; kk < KS; ++kk) {
    a0[kk] = *(const half8*)(Wg + ((mt0 * KC + kk * 4 + quad) * 16 + l16) * 8);
    a1[kk] = *(const half8*)(Wg + ((mt1 * KC + kk * 4 + quad) * 16 + l16) * 8);
  }
  float4_t acc0[NTT], acc1[NTT];
#pragma unroll
  for (int nt = 0; nt < NTT; ++nt) {
    acc0[nt] = (float4_t){0.f, 0.f, 0.f, 0.f};
    acc1[nt] = (float4_t){0.f, 0.f, 0.f, 0.f};
  }
#pragma unroll
  for (int kk = 0; kk < KS; ++kk) {
#pragma unroll
    for (int nt = 0; nt < NTT; ++nt) {
      half8 b = *(const half8*)(inB + (kk * 4 + quad) * RS + (nt * 16 + l16) * 8);
      acc0[nt] = __builtin_amdgcn_mfma_f32_16x16x32_f16(a0[kk], b, acc0[nt], 0, 0, 0);
      acc1[nt] = __builtin_amdgcn_mfma_f32_16x16x32_f16(a1[kk], b, acc1[nt], 0, 0, 0);
    }
  }
  const float4_t bv0 = *(const float4_t*)(biasG + mt0 * 16 + quad * 4);
  const float4_t bv1 = *(const float4_t*)(biasG + mt1 * 16 + quad * 4);
  const int ob0 = mt0 * 16 + quad * 4;
  const int ob1 = mt1 * 16 + quad * 4;
#pragma unroll
  for (int nt = 0; nt < NTT; ++nt) {
    const int s = nt * 16 + l16;
    half4_t h0, h1;
#pragma unroll
    for (int r = 0; r < 4; ++r) {
      h0[r] = (_Float16)fast_tanh(acc0[nt][r] + bv0[r]);
      h1[r] = (_Float16)fast_tanh(acc1[nt][r] + bv1[r]);
    }
    *(half4_t*)(outB + (ob0 >> 3) * RS + s * 8 + (ob0 & 7)) = h0;
    *(half4_t*)(outB + (ob1 >> 3) * RS + s * 8 + (ob1 & 7)) = h1;
  }
}

__global__ __launch_bounds__(NT, 5) void bnet_main(
    const float* __restrict__ x, const float* __restrict__ meang,
    const float* __restrict__ stdg, const float* __restrict__ b31,
    const float* __restrict__ b32, const _Float16* __restrict__ ws,
    float* __restrict__ out) {
  __shared__ __align__(16) _Float16 bufH[SB * 128];
  __shared__ __align__(16) _Float16 bufA[SB * 128];
  __shared__ __align__(16) _Float16 bufB[SB * 128];
  __shared__ __align__(16) unsigned char uni[NT * 5 * 4];  // xb (2KB) then part (5KB)

  _Float16* xb = (_Float16*)uni;          // [4 chunks][SB][8] = SB*32
  float* part = (float*)uni;              // [NT][5]

  const int tid = threadIdx.x;
  const int s0 = blockIdx.x * SB;
  const float* biasW = (const float*)(ws + OFF_BIAS);

  // stage x -> xb chunk-major (K=32, zero-padded past k=5)
  if (tid < 128) {
    const int s = tid & 31, k8 = tid >> 5;
    half8 v;
#pragma unroll
    for (int j = 0; j < 8; ++j) v[j] = (_Float16)0.f;
    if (k8 == 0) {
      const float* xp = x + (size_t)(s0 + s) * 6;
#pragma unroll
      for (int j = 0; j < 6; ++j) v[j] = (_Float16)xp[j];
    }
    *(half8*)(xb + k8 * (SB * 8) + s * 8) = v;
  }
  __syncthreads();

  gemm_layer<32, SB>(ws + OFF_W1, xb, biasW, bufH);               // h
  __syncthreads();
  gemm_layer<128, SB>(ws + OFF_W21, bufH, biasW + 128, bufA);     // x21
  gemm_layer<128, SB>(ws + OFF_W22, bufH, biasW + 256, bufB);     // x22
  __syncthreads();
  gemm_layer<128, SB>(ws + OFF_WM1, bufA, biasW + 384, bufH);     // xm1 -> bufH
  __syncthreads();
  gemm_layer<128, SB>(ws + OFF_WM2, bufB, biasW + 512, bufA);     // xm2 -> bufA
  __syncthreads();

  // L4 partials: 5 outputs x 32 samples, k split over 8 segments of 16
  {
    const int s = tid & 31, q = tid >> 5;
    half8 xm1a = *(const half8*)(bufH + (2 * q + 0) * (SB * 8) + s * 8);
    half8 xm1b = *(const half8*)(bufH + (2 * q + 1) * (SB * 8) + s * 8);
    half8 xm2a = *(const half8*)(bufA + (2 * q + 0) * (SB * 8) + s * 8);
    half8 xm2b = *(const half8*)(bufA + (2 * q + 1) * (SB * 8) + s * 8);
    float res[5];
#pragma unroll
    for (int j = 0; j < 5; ++j) {
      const _Float16* wr = ws + OFF_W4 + j * 128 + q * 16;
      half8 wa = *(const half8*)(wr);
      half8 wb = *(const half8*)(wr + 8);
      half8 xa = (j < 3) ? xm1a : xm2a;
      half8 xc = (j < 3) ? xm1b : xm2b;
      float acc = 0.f;
#pragma unroll
      for (int e = 0; e < 8; ++e) acc = fmaf((float)xa[e], (float)wa[e], acc);
#pragma unroll
      for (int e = 0; e < 8; ++e) acc = fmaf((float)xc[e], (float)wb[e], acc);
      res[j] = acc;
    }
    __syncthreads();  // xb region dead; reuse as part
#pragma unroll
    for (int j = 0; j < 5; ++j) part[tid * 5 + j] = res[j];
  }
  __syncthreads();

  if (tid < SB) {
    const int s = tid;
    float r[5];
#pragma unroll
    for (int j = 0; j < 5; ++j) {
      float a = 0.f;
#pragma unroll
      for (int q = 0; q < 8; ++q) a += part[(q * 32 + s) * 5 + j];
      r[j] = a;
    }
    float u0 = -(r[0] + b31[0]);
    float u1 = -(r[1] + b31[1]);
    float u2 = -(r[2] + b31[2]);
    float p0 = sigmoid4(r[3] + b32[0]);
    float p1 = sigmoid4(r[4] + b32[1]);
    const float* xp = x + (size_t)(s0 + s) * 6;
    float px = xp[0] * stdg[0] + meang[0];
    float vx = xp[1] * stdg[1] + meang[1];
    float py = xp[2] * stdg[2] + meang[2];
    float vy = xp[3] * stdg[3] + meang[3];
    float pz = xp[4] * stdg[4] + meang[4];
    float vz = xp[5] * stdg[5] + meang[5];
    float dx = px - 10.f, dy = py - 10.f, dz = pz - 9.f;
    float dx2 = dx * dx, dy2 = dy * dy, dz2 = dz * dz;
    float dx3 = dx2 * dx, dy3 = dy2 * dy, dz3 = dz2 * dz;
    float barrier = dx3 * dx + dy3 * dy + dz3 * dz - 2401.f;  // R^4 = 7^4
    float bdot = 4.f * (dx3 * vx + dy3 * vy + dz3 * vz);
    float Lf2b = 12.f * (dx2 * vx * vx + dy2 * vy * vy + dz2 * vz * vz);
    float g0 = -4.f * dx3, g1 = -4.f * dy3, g2 = -4.f * dz3;
    float hv = Lf2b + (p0 + p1) * bdot + p0 * p1 * barrier;
    float Gu = g0 * u0 + g1 * u1 + g2 * u2;
    float GG = g0 * g0 + g1 * g1 + g2 * g2;
    float lam = fmaxf(Gu - hv, 0.f) / GG;
    float* op = out + (size_t)(s0 + s) * 3;
    op[0] = u0 - lam * g0;
    op[1] = u1 - lam * g1;
    op[2] = u2 - lam * g2;
  }
}

extern "C" void kernel_launch(void* const* d_in, const int* in_sizes, int n_in,
                              void* d_out, int out_size, void* d_ws, size_t ws_size,
                              hipStream_t stream) {
  const float* x    = (const float*)d_in[0];
  const float* mean = (const float*)d_in[1];
  const float* stdv = (const float*)d_in[2];
  const float* w1   = (const float*)d_in[3];
  const float* b1   = (const float*)d_in[4];
  const float* w21  = (const float*)d_in[5];
  const float* b21  = (const float*)d_in[6];
  const float* w22  = (const float*)d_in[7];
  const float* b22  = (const float*)d_in[8];
  const float* wm1  = (const float*)d_in[9];
  const float* bm1  = (const float*)d_in[10];
  const float* wm2  = (const float*)d_in[11];
  const float* bm2  = (const float*)d_in[12];
  const float* w31  = (const float*)d_in[13];
  const float* b31  = (const float*)d_in[14];
  const float* w32  = (const float*)d_in[15];
  const float* b32  = (const float*)d_in[16];
  _Float16* ws = (_Float16*)d_ws;
  float* out = (float*)d_out;
  const int batch = in_sizes[0] / 6;

  hipLaunchKernelGGL(prepack, dim3(96), dim3(NT), 0, stream,
                     w1, w21, w22, wm1, wm2, w31, w32,
                     b1, b21, b22, bm1, bm2, ws);
  hipLaunchKernelGGL(bnet_main, dim3(batch / SB), dim3(NT), 0, stream,
                     x, mean, stdv, b31, b32, (const _Float16*)ws, out);
}